// Round 1
// baseline (627.362 us; speedup 1.0000x reference)
//
#include <hip/hip_runtime.h>
#include <math.h>

#define NSUB 16
#define NLAB 8
#define KG 128
#define BN 16384
#define DD 1024

// K0: gid per b-row + group histogram
__global__ __launch_bounds__(256) void k0_gid(const int* __restrict__ subject,
                                              const int* __restrict__ labels,
                                              int* __restrict__ gid, int* __restrict__ cnt) {
    int b = blockIdx.x * 256 + threadIdx.x;
    int g = subject[b] * NLAB + labels[b];
    gid[b] = g;
    atomicAdd(&cnt[g], 1);
}

// K1: segment sums of X over groups (both c copies). Block = 512 b-rows x 64 dims.
__global__ __launch_bounds__(256) void k1_sums(const float* __restrict__ X,
                                               const int* __restrict__ gid,
                                               float* __restrict__ sums) {
    int bc = blockIdx.x >> 4;   // 0..31 b-chunk (512 rows)
    int dc = blockIdx.x & 15;   // 0..15 d-chunk (64 dims)
    int d0 = dc * 64, b0 = bc * 512;
    __shared__ float acc[KG * 64];   // 32 KB
    __shared__ int gidl[512];
    int t = threadIdx.x;
    for (int i = t; i < KG * 64; i += 256) acc[i] = 0.f;
    for (int i = t; i < 512; i += 256) gidl[i] = gid[b0 + i];
    __syncthreads();
    int d = t & 63, p0 = t >> 6;
    for (int it = 0; it < 64; ++it) {
        float v[4]; int gg[4];
#pragma unroll
        for (int u = 0; u < 4; ++u) {
            int pair = it * 16 + u * 4 + p0;   // 0..1023  (512 b x 2 c)
            int bl = pair >> 1, c = pair & 1;
            v[u] = X[(size_t)(b0 + bl) * 2048 + (size_t)c * 1024 + d0 + d];
            gg[u] = gidl[bl];
        }
#pragma unroll
        for (int u = 0; u < 4; ++u) atomicAdd(&acc[gg[u] * 64 + d], v[u]);
    }
    __syncthreads();
    for (int i = t; i < KG * 64; i += 256)
        atomicAdd(&sums[(size_t)(i >> 6) * DD + d0 + (i & 63)], acc[i]);
}

// K2: centroid = sums / counts
__global__ __launch_bounds__(256) void k2_centroid(const float* __restrict__ sums,
                                                   const int* __restrict__ cnt,
                                                   float* __restrict__ centroid) {
    int idx = blockIdx.x * 256 + threadIdx.x;   // 131072
    int g = idx >> 10;
    centroid[idx] = sums[idx] / (2.f * (float)cnt[g]);
}

// K3: per-row ||feat - centroid||, accumulate sqrt(dist) per group. One wave per row.
__global__ __launch_bounds__(256) void k3_dist(const float* __restrict__ X,
                                               const int* __restrict__ gid,
                                               const float* __restrict__ centroid,
                                               float* __restrict__ sqrtsum) {
    int i = blockIdx.x * 4 + (threadIdx.x >> 6);   // row 0..32767
    int lane = threadIdx.x & 63;
    int b = i & (BN - 1), c = i >> 14;
    int g = gid[b];
    const float4* xr = (const float4*)(X + (size_t)b * 2048 + (size_t)c * 1024);
    const float4* cr = (const float4*)(centroid + (size_t)g * 1024);
    float acc = 0.f;
#pragma unroll
    for (int j = 0; j < 4; ++j) {
        float4 xv = xr[lane + j * 64];
        float4 cv = cr[lane + j * 64];
        float dx = xv.x - cv.x, dy = xv.y - cv.y, dz = xv.z - cv.z, dw = xv.w - cv.w;
        acc += dx * dx + dy * dy + dz * dz + dw * dw;
    }
#pragma unroll
    for (int m = 32; m; m >>= 1) acc += __shfl_xor(acc, m, 64);
    if (lane == 0) atomicAdd(&sqrtsum[g], sqrtf(sqrtf(acc)));   // sqrt(dist), dist = sqrt(acc)
}

// K4: density post-processing (max/where, rank-based quantiles, clip, mean-normalize)
__global__ void k4_density(const float* __restrict__ sqrtsum,
                           const int* __restrict__ cnt,
                           float* __restrict__ recipDen) {
    __shared__ float tmp[KG];
    __shared__ float d1s[KG];
    __shared__ float qv[4];
    int g = threadIdx.x;
    float cntf = 2.f * (float)cnt[g];
    float d0 = (sqrtsum[g] / cntf) / logf(cntf + 10.f);
    tmp[g] = d0;
    __syncthreads();
    float dmax = -INFINITY;
    for (int j = 0; j < KG; ++j) dmax = fmaxf(dmax, tmp[j]);
    float v = (cntf <= 1.f) ? dmax : d0;
    d1s[g] = v;
    __syncthreads();
    int less = 0, eq = 0;
    for (int j = 0; j < KG; ++j) {
        float u = d1s[j];
        less += (u < v) ? 1 : 0;
        eq += (u == v) ? 1 : 0;
    }
    // quantile(0.1): idx 12.7 -> 0.3*v[12]+0.7*v[13]; quantile(0.9): idx 114.3 -> 0.7*v[114]+0.3*v[115]
    const int ppos[4] = {12, 13, 114, 115};
    for (int q = 0; q < 4; ++q)
        if (less <= ppos[q] && ppos[q] < less + eq) qv[q] = v;
    __syncthreads();
    float q10 = 0.3f * qv[0] + 0.7f * qv[1];
    float q90 = 0.7f * qv[2] + 0.3f * qv[3];
    float d2 = fminf(fmaxf(v, q10), q90);
    __syncthreads();
    tmp[g] = d2;
    __syncthreads();
    float sum = 0.f;
    for (int j = 0; j < KG; ++j) sum += tmp[j];
    float mean = sum / (float)KG;
    float den = 0.1f * d2 / mean;
    recipDen[g] = 1.f / den;
}

// K5: sim = feat @ centroid^T * recipDen, fused softmax-CE epilogue -> scalar loss.
// Block computes 32 rows x 128 groups; thread = 4 rows x 4 strided groups.
__global__ __launch_bounds__(256) void k5_loss(const float* __restrict__ X,
                                               const int* __restrict__ gid,
                                               const float* __restrict__ centroid,
                                               const float* __restrict__ recipDen,
                                               float* __restrict__ out) {
    __shared__ float lds_c[KG * 65];   // 33.3 KB, pad 65 to break bank conflicts
    __shared__ float lds_f[32 * 65];   //  8.3 KB
    int t = threadIdx.x;
    int row0 = blockIdx.x * 32;
    float acc[4][4];
#pragma unroll
    for (int j = 0; j < 4; ++j)
#pragma unroll
        for (int m = 0; m < 4; ++m) acc[j][m] = 0.f;
    int tg = t & 31;    // group lane: groups tg + 32m
    int tq = t >> 5;    // row quad: rows 4*tq..4*tq+3
    int k = t & 63, rr = t >> 6;
    for (int kc = 0; kc < 16; ++kc) {
        int k0 = kc * 64;
#pragma unroll
        for (int rb = 0; rb < 8; ++rb) {
            int r = rb * 4 + rr;
            int row = row0 + r;
            int b = row & (BN - 1), c = row >> 14;
            lds_f[r * 65 + k] = X[(size_t)b * 2048 + (size_t)c * 1024 + k0 + k];
        }
#pragma unroll
        for (int gb = 0; gb < 32; ++gb) {
            int g = gb * 4 + rr;
            lds_c[g * 65 + k] = centroid[(size_t)g * DD + k0 + k];
        }
        __syncthreads();
#pragma unroll 4
        for (int kk = 0; kk < 64; ++kk) {
            float fv[4], cv[4];
#pragma unroll
            for (int j = 0; j < 4; ++j) fv[j] = lds_f[(tq * 4 + j) * 65 + kk];
#pragma unroll
            for (int m = 0; m < 4; ++m) cv[m] = lds_c[(tg + 32 * m) * 65 + kk];
#pragma unroll
            for (int j = 0; j < 4; ++j)
#pragma unroll
                for (int m = 0; m < 4; ++m) acc[j][m] += fv[j] * cv[m];
        }
        __syncthreads();
    }
    float cden[4];
#pragma unroll
    for (int m = 0; m < 4; ++m) cden[m] = recipDen[tg + 32 * m];
    float loss_local = 0.f;
#pragma unroll
    for (int j = 0; j < 4; ++j) {
        int row = row0 + tq * 4 + j;
        int b = row & (BN - 1);
        int gb_ = gid[b];
        int s = gb_ >> 3, l = gb_ & 7;
        float sim[4];
        float mx = -INFINITY;
#pragma unroll
        for (int m = 0; m < 4; ++m) {
            sim[m] = acc[j][m] * cden[m];
            mx = fmaxf(mx, sim[m]);
        }
#pragma unroll
        for (int x = 16; x; x >>= 1) mx = fmaxf(mx, __shfl_xor(mx, x, 64));
        float S = 0.f, P = 0.f;
#pragma unroll
        for (int m = 0; m < 4; ++m) {
            int g = tg + 32 * m;
            bool posm = ((g & 7) == l) && ((g >> 3) != s);
            if (posm) {
                float pv = sim[m] - mx;
                S += expf(pv);
                P += pv;
            }
        }
#pragma unroll
        for (int x = 16; x; x >>= 1) {
            S += __shfl_xor(S, x, 64);
            P += __shfl_xor(P, x, 64);
        }
        // 113 masked-out entries contribute exp(0)=1 each to the softmax denominator
        if (tg == 0) loss_local += logf(113.f + S) - P * (1.f / 15.f);
    }
    if (tg == 0) atomicAdd(out, loss_local * (1.f / 32768.f));
}

extern "C" void kernel_launch(void* const* d_in, const int* in_sizes, int n_in,
                              void* d_out, int out_size, void* d_ws, size_t ws_size,
                              hipStream_t stream) {
    const float* X = (const float*)d_in[0];
    const int* subject = (const int*)d_in[1];
    const int* labels = (const int*)d_in[2];
    float* out = (float*)d_out;
    char* w = (char*)d_ws;
    int* gid = (int*)(w + 0);                 // 64 KB
    int* cnt = (int*)(w + 65536);             // 512 B
    float* sqrtsum = (float*)(w + 66048);     // 512 B
    float* recipDen = (float*)(w + 66560);    // 512 B
    float* sums = (float*)(w + 131072);       // 512 KB
    float* centroid = (float*)(w + 655360);   // 512 KB  (total ~1.13 MB)

    hipMemsetAsync(cnt, 0, KG * sizeof(int), stream);
    hipMemsetAsync(sqrtsum, 0, KG * sizeof(float), stream);
    hipMemsetAsync(sums, 0, (size_t)KG * DD * sizeof(float), stream);
    hipMemsetAsync(out, 0, sizeof(float), stream);

    k0_gid<<<BN / 256, 256, 0, stream>>>(subject, labels, gid, cnt);
    k1_sums<<<512, 256, 0, stream>>>(X, gid, sums);
    k2_centroid<<<KG * DD / 256, 256, 0, stream>>>(sums, cnt, centroid);
    k3_dist<<<32768 / 4, 256, 0, stream>>>(X, gid, centroid, sqrtsum);
    k4_density<<<1, 128, 0, stream>>>(sqrtsum, cnt, recipDen);
    k5_loss<<<1024, 256, 0, stream>>>(X, gid, centroid, recipDen, out);
}

// Round 2
// 401.522 us; speedup vs baseline: 1.5625x; 1.5625x over previous
//
#include <hip/hip_runtime.h>
#include <math.h>

#define NSUB 16
#define NLAB 8
#define KG 128
#define BN 16384
#define DD 1024

typedef float v4f __attribute__((ext_vector_type(4)));
typedef short short8v __attribute__((ext_vector_type(8)));

static __device__ __forceinline__ short f2bf(float f) {
    unsigned u = __builtin_bit_cast(unsigned, f);
    unsigned r = (u + 0x7fffu + ((u >> 16) & 1u)) >> 16;   // RNE
    return (short)r;
}

// K0: gid per b-row + group histogram
__global__ __launch_bounds__(256) void k0_gid(const int* __restrict__ subject,
                                              const int* __restrict__ labels,
                                              int* __restrict__ gid, int* __restrict__ cnt) {
    int b = blockIdx.x * 256 + threadIdx.x;
    int g = subject[b] * NLAB + labels[b];
    gid[b] = g;
    atomicAdd(&cnt[g], 1);
}

// K0b: exclusive prefix over 128 counts -> offs, cursor
__global__ void k0b_offs(const int* __restrict__ cnt, int* __restrict__ offs,
                         int* __restrict__ cursor) {
    __shared__ int c[KG];
    int t = threadIdx.x;
    c[t] = cnt[t];
    __syncthreads();
    int o = 0;
    for (int j = 0; j < t; ++j) o += c[j];
    offs[t] = o;
    cursor[t] = o;
}

// K0c: scatter row indices into per-group lists (counting sort)
__global__ __launch_bounds__(256) void k0c_scatter(const int* __restrict__ gid,
                                                   int* __restrict__ cursor,
                                                   int* __restrict__ rowlist) {
    int b = blockIdx.x * 256 + threadIdx.x;
    int pos = atomicAdd(&cursor[gid[b]], 1);
    rowlist[pos] = b;
}

// K1: centroid for (group g, d-quarter). No atomics: each block owns its output.
__global__ __launch_bounds__(256) void k1_centroid(const float* __restrict__ X,
                                                   const int* __restrict__ rowlist,
                                                   const int* __restrict__ offs,
                                                   const int* __restrict__ cnt,
                                                   float* __restrict__ centroid) {
    int g = blockIdx.x >> 2;
    int dq = blockIdx.x & 3;
    int d = dq * 256 + threadIdx.x;
    __shared__ int rows[512];
    int n = cnt[g], o = offs[g];
    for (int i = threadIdx.x; i < n && i < 512; i += 256) rows[i] = rowlist[o + i];
    __syncthreads();
    float acc = 0.f;
    int i = 0;
    for (; i + 4 <= n; i += 4) {
#pragma unroll
        for (int u = 0; u < 4; ++u) {
            size_t base = (size_t)rows[i + u] * 2048 + d;
            acc += X[base] + X[base + 1024];
        }
    }
    for (; i < n; ++i) {
        size_t base = (size_t)rows[i] * 2048 + d;
        acc += X[base] + X[base + 1024];
    }
    centroid[(size_t)g * DD + d] = acc / (2.f * (float)n);
}

// K3: per-row ||feat - centroid||, accumulate sqrt(dist) per group. One wave per row.
__global__ __launch_bounds__(256) void k3_dist(const float* __restrict__ X,
                                               const int* __restrict__ gid,
                                               const float* __restrict__ centroid,
                                               float* __restrict__ sqrtsum) {
    int i = blockIdx.x * 4 + (threadIdx.x >> 6);   // row 0..32767
    int lane = threadIdx.x & 63;
    int b = i & (BN - 1), c = i >> 14;
    int g = gid[b];
    const float4* xr = (const float4*)(X + (size_t)b * 2048 + (size_t)c * 1024);
    const float4* cr = (const float4*)(centroid + (size_t)g * 1024);
    float acc = 0.f;
#pragma unroll
    for (int j = 0; j < 4; ++j) {
        float4 xv = xr[lane + j * 64];
        float4 cv = cr[lane + j * 64];
        float dx = xv.x - cv.x, dy = xv.y - cv.y, dz = xv.z - cv.z, dw = xv.w - cv.w;
        acc += dx * dx + dy * dy + dz * dz + dw * dw;
    }
#pragma unroll
    for (int m = 32; m; m >>= 1) acc += __shfl_xor(acc, m, 64);
    if (lane == 0) atomicAdd(&sqrtsum[g], sqrtf(sqrtf(acc)));   // sqrt(dist), dist = sqrt(acc)
}

// K4: density post-processing (max/where, rank-based quantiles, clip, mean-normalize)
__global__ void k4_density(const float* __restrict__ sqrtsum,
                           const int* __restrict__ cnt,
                           float* __restrict__ recipDen) {
    __shared__ float tmp[KG];
    __shared__ float d1s[KG];
    __shared__ float qv[4];
    int g = threadIdx.x;
    float cntf = 2.f * (float)cnt[g];
    float d0 = (sqrtsum[g] / cntf) / logf(cntf + 10.f);
    tmp[g] = d0;
    __syncthreads();
    float dmax = -INFINITY;
    for (int j = 0; j < KG; ++j) dmax = fmaxf(dmax, tmp[j]);
    float v = (cntf <= 1.f) ? dmax : d0;
    d1s[g] = v;
    __syncthreads();
    int less = 0, eq = 0;
    for (int j = 0; j < KG; ++j) {
        float u = d1s[j];
        less += (u < v) ? 1 : 0;
        eq += (u == v) ? 1 : 0;
    }
    // quantile(0.1): idx 12.7 -> 0.3*v[12]+0.7*v[13]; quantile(0.9): idx 114.3 -> 0.7*v[114]+0.3*v[115]
    const int ppos[4] = {12, 13, 114, 115};
    for (int q = 0; q < 4; ++q)
        if (less <= ppos[q] && ppos[q] < less + eq) qv[q] = v;
    __syncthreads();
    float q10 = 0.3f * qv[0] + 0.7f * qv[1];
    float q90 = 0.7f * qv[2] + 0.3f * qv[3];
    float d2 = fminf(fmaxf(v, q10), q90);
    __syncthreads();
    tmp[g] = d2;
    __syncthreads();
    float sum = 0.f;
    for (int j = 0; j < KG; ++j) sum += tmp[j];
    float mean = sum / (float)KG;
    float den = 0.1f * d2 / mean;
    recipDen[g] = 1.f / den;
}

// K5: bf16-MFMA matmul sim = feat @ centroid^T, fused density-scale + softmax-CE.
// Block = 64 rows, 4 waves (16 rows each), 128 groups. K-chunks of 32.
// LDS holds A/B tiles pre-arranged in MFMA fragment order (lane-contiguous 16 B).
__global__ __launch_bounds__(256) void k5_loss(const float* __restrict__ X,
                                               const int* __restrict__ gid,
                                               const float* __restrict__ centroid,
                                               const float* __restrict__ recipDen,
                                               float* __restrict__ out) {
    __shared__ __align__(16) short sA[4 * 64 * 8];   // 4 row-tiles x 64 lanes x 8 bf16 = 4 KB
    __shared__ __align__(16) short sB[8 * 64 * 8];   // 8 grp-tiles x 64 lanes x 8 bf16 = 8 KB
    int t = threadIdx.x;
    int w = t >> 6, lane = t & 63;
    int row0 = blockIdx.x * 64;
    v4f acc[8];
#pragma unroll
    for (int i = 0; i < 8; ++i) acc[i] = (v4f){0.f, 0.f, 0.f, 0.f};
    // staging decomposition: thread -> (sub-row rsub, k-piece kq); float4 at k = kq*4
    int rsub = t >> 3;          // 0..31
    int kq = t & 7;             // 0..7
    int quad = kq >> 1;         // (kq*4)>>3
    int j0 = (kq & 1) * 4;      // (kq*4)&7

    for (int kc = 0; kc < 32; ++kc) {
        int k0 = kc * 32;
        // stage A (rows): 64 rows x 32 k, fragment order: A[m=lane&15][k=quad*8+j]
#pragma unroll
        for (int p = 0; p < 2; ++p) {
            int r = p * 32 + rsub;
            int row = row0 + r;
            int b = row & (BN - 1), c = row >> 14;
            float4 v = *(const float4*)(X + (size_t)b * 2048 + (size_t)c * 1024 + k0 + kq * 4);
            short4 bv = make_short4(f2bf(v.x), f2bf(v.y), f2bf(v.z), f2bf(v.w));
            *(short4*)&sA[(r >> 4) * 512 + (quad * 16 + (r & 15)) * 8 + j0] = bv;
        }
        // stage B (groups): 128 groups x 32 k, fragment order: B[k=quad*8+j][n=g&15] = centroid[g][k]
#pragma unroll
        for (int p = 0; p < 4; ++p) {
            int g = p * 32 + rsub;
            float4 v = *(const float4*)(centroid + (size_t)g * DD + k0 + kq * 4);
            short4 bv = make_short4(f2bf(v.x), f2bf(v.y), f2bf(v.z), f2bf(v.w));
            *(short4*)&sB[(g >> 4) * 512 + (quad * 16 + (g & 15)) * 8 + j0] = bv;
        }
        __syncthreads();
        short8v a = *(short8v*)&sA[w * 512 + lane * 8];
#pragma unroll
        for (int gt = 0; gt < 8; ++gt) {
            short8v b8 = *(short8v*)&sB[gt * 512 + lane * 8];
            acc[gt] = __builtin_amdgcn_mfma_f32_16x16x32_bf16(a, b8, acc[gt], 0, 0, 0);
        }
        __syncthreads();
    }

    // epilogue: C/D layout col = lane&15, row = (lane>>4)*4 + reg
    int cg = lane & 15, q = lane >> 4;
    float cden[8];
#pragma unroll
    for (int gt = 0; gt < 8; ++gt) cden[gt] = recipDen[gt * 16 + cg];
    float loss_local = 0.f;
#pragma unroll
    for (int reg = 0; reg < 4; ++reg) {
        int row = row0 + w * 16 + q * 4 + reg;
        int b = row & (BN - 1);
        int gb = gid[b];
        int s = gb >> 3, l = gb & 7;
        float sim[8];
        float mx = -INFINITY;
#pragma unroll
        for (int gt = 0; gt < 8; ++gt) {
            sim[gt] = acc[gt][reg] * cden[gt];
            mx = fmaxf(mx, sim[gt]);
        }
#pragma unroll
        for (int x = 1; x < 16; x <<= 1) mx = fmaxf(mx, __shfl_xor(mx, x, 64));
        float S = 0.f, P = 0.f;
#pragma unroll
        for (int gt = 0; gt < 8; ++gt) {
            int g = gt * 16 + cg;
            if (((g & 7) == l) && ((g >> 3) != s)) {
                float pv = sim[gt] - mx;
                S += expf(pv);
                P += pv;
            }
        }
#pragma unroll
        for (int x = 1; x < 16; x <<= 1) {
            S += __shfl_xor(S, x, 64);
            P += __shfl_xor(P, x, 64);
        }
        // 113 masked-out entries contribute exp(0)=1 each to the softmax denominator
        if (cg == 0) loss_local += logf(113.f + S) - P * (1.f / 15.f);
    }
    if (cg == 0) atomicAdd(out, loss_local * (1.f / 32768.f));
}

extern "C" void kernel_launch(void* const* d_in, const int* in_sizes, int n_in,
                              void* d_out, int out_size, void* d_ws, size_t ws_size,
                              hipStream_t stream) {
    const float* X = (const float*)d_in[0];
    const int* subject = (const int*)d_in[1];
    const int* labels = (const int*)d_in[2];
    float* out = (float*)d_out;
    char* w = (char*)d_ws;
    int* gid = (int*)(w + 0);                 // 64 KB
    int* cnt = (int*)(w + 65536);             // 512 B
    int* offs = (int*)(w + 66048);            // 512 B
    int* cursor = (int*)(w + 66560);          // 512 B
    float* sqrtsum = (float*)(w + 67072);     // 512 B
    float* recipDen = (float*)(w + 67584);    // 512 B
    int* rowlist = (int*)(w + 131072);        // 64 KB
    float* centroid = (float*)(w + 262144);   // 512 KB   (total ~768 KB)

    hipMemsetAsync(cnt, 0, KG * sizeof(int), stream);
    hipMemsetAsync(sqrtsum, 0, KG * sizeof(float), stream);
    hipMemsetAsync(out, 0, sizeof(float), stream);

    k0_gid<<<BN / 256, 256, 0, stream>>>(subject, labels, gid, cnt);
    k0b_offs<<<1, KG, 0, stream>>>(cnt, offs, cursor);
    k0c_scatter<<<BN / 256, 256, 0, stream>>>(gid, cursor, rowlist);
    k1_centroid<<<KG * 4, 256, 0, stream>>>(X, rowlist, offs, cnt, centroid);
    k3_dist<<<32768 / 4, 256, 0, stream>>>(X, gid, centroid, sqrtsum);
    k4_density<<<1, KG, 0, stream>>>(sqrtsum, cnt, recipDen);
    k5_loss<<<32768 / 64, 256, 0, stream>>>(X, gid, centroid, recipDen, out);
}

// Round 3
// 289.856 us; speedup vs baseline: 2.1644x; 1.3852x over previous
//
#include <hip/hip_runtime.h>
#include <hip/hip_bf16.h>
#include <math.h>

#define NSUB 16
#define NLAB 8
#define KG 128
#define BN 16384
#define DD 1024

typedef float v4f __attribute__((ext_vector_type(4)));
typedef short short8v __attribute__((ext_vector_type(8)));

static __device__ __forceinline__ short f2bf(float f) {
    unsigned u = __builtin_bit_cast(unsigned, f);
    unsigned r = (u + 0x7fffu + ((u >> 16) & 1u)) >> 16;   // RNE
    return (short)r;
}

static __device__ __forceinline__ short8v pack_bf8(float4 lo, float4 hi) {
    union { short8v s; __hip_bfloat162 h[4]; } u;
    u.h[0] = __float22bfloat162_rn(float2{lo.x, lo.y});
    u.h[1] = __float22bfloat162_rn(float2{lo.z, lo.w});
    u.h[2] = __float22bfloat162_rn(float2{hi.x, hi.y});
    u.h[3] = __float22bfloat162_rn(float2{hi.z, hi.w});
    return u.s;
}

// K0: gid + group histogram via LDS (16 blocks x 1024 -> 2048 global atomics)
__global__ __launch_bounds__(1024) void k0_gid(const int* __restrict__ subject,
                                               const int* __restrict__ labels,
                                               int* __restrict__ gid, int* __restrict__ cnt) {
    __shared__ int h[KG];
    int t = threadIdx.x;
    if (t < KG) h[t] = 0;
    __syncthreads();
    int b = blockIdx.x * 1024 + t;
    int g = subject[b] * NLAB + labels[b];
    gid[b] = g;
    atomicAdd(&h[g], 1);
    __syncthreads();
    if (t < KG && h[t]) atomicAdd(&cnt[t], h[t]);
}

// K0b: exclusive prefix over 128 counts -> offs, cursor
__global__ void k0b_offs(const int* __restrict__ cnt, int* __restrict__ offs,
                         int* __restrict__ cursor) {
    __shared__ int c[KG];
    int t = threadIdx.x;
    c[t] = cnt[t];
    __syncthreads();
    int o = 0;
    for (int j = 0; j < t; ++j) o += c[j];
    offs[t] = o;
    cursor[t] = o;
}

// K0c: block-local counting sort -> per-block chunk reservation (2048 global atomics)
__global__ __launch_bounds__(1024) void k0c_scatter(const int* __restrict__ gid,
                                                    int* __restrict__ cursor,
                                                    int* __restrict__ rowlist) {
    __shared__ int lcnt[KG], lbase[KG], lcur[KG];
    int t = threadIdx.x;
    if (t < KG) { lcnt[t] = 0; lcur[t] = 0; }
    __syncthreads();
    int b = blockIdx.x * 1024 + t;
    int g = gid[b];
    atomicAdd(&lcnt[g], 1);
    __syncthreads();
    if (t < KG) lbase[t] = lcnt[t] ? atomicAdd(&cursor[t], lcnt[t]) : 0;
    __syncthreads();
    int pos = lbase[g] + atomicAdd(&lcur[g], 1);
    rowlist[pos] = b;
}

// K1: centroid for (group g, d-quarter). No atomics: each block owns its output.
__global__ __launch_bounds__(256) void k1_centroid(const float* __restrict__ X,
                                                   const int* __restrict__ rowlist,
                                                   const int* __restrict__ offs,
                                                   const int* __restrict__ cnt,
                                                   float* __restrict__ centroid) {
    int g = blockIdx.x >> 2;
    int dq = blockIdx.x & 3;
    int d = dq * 256 + threadIdx.x;
    __shared__ int rows[512];
    int n = cnt[g], o = offs[g];
    if (n > 512) n = 512;
    for (int i = threadIdx.x; i < n; i += 256) rows[i] = rowlist[o + i];
    __syncthreads();
    float acc = 0.f;
    int i = 0;
    for (; i + 8 <= n; i += 8) {
        float v[16];
#pragma unroll
        for (int u = 0; u < 8; ++u) {
            size_t base = (size_t)rows[i + u] * 2048 + d;
            v[2 * u] = X[base];
            v[2 * u + 1] = X[base + 1024];
        }
#pragma unroll
        for (int u = 0; u < 16; ++u) acc += v[u];
    }
    for (; i < n; ++i) {
        size_t base = (size_t)rows[i] * 2048 + d;
        acc += X[base] + X[base + 1024];
    }
    centroid[(size_t)g * DD + d] = acc / (2.f * (float)n);
}

// K2b: centroid -> bf16 table for k5
__global__ __launch_bounds__(256) void k2b_cbf(const float* __restrict__ centroid,
                                               unsigned short* __restrict__ Cbf) {
    int i = blockIdx.x * 256 + threadIdx.x;   // 131072
    Cbf[i] = (unsigned short)f2bf(centroid[i]);
}

// K3: group-blocked distances. Block = (group, chunk); centroid in LDS; 1 atomic/block.
__global__ __launch_bounds__(256) void k3_dist(const float* __restrict__ X,
                                               const int* __restrict__ rowlist,
                                               const int* __restrict__ offs,
                                               const int* __restrict__ cnt,
                                               const float* __restrict__ centroid,
                                               float* __restrict__ sqrtsum) {
    int g = blockIdx.x >> 3;
    int ch = blockIdx.x & 7;
    int t = threadIdx.x, w = t >> 6, lane = t & 63;
    __shared__ float cent[DD];
    __shared__ int rows[512];
    __shared__ float bsum;
    for (int i = t; i < DD; i += 256) cent[i] = centroid[(size_t)g * DD + i];
    int n = cnt[g], o = offs[g];
    if (n > 512) n = 512;
    for (int i = t; i < n; i += 256) rows[i] = rowlist[o + i];
    if (t == 0) bsum = 0.f;
    __syncthreads();
    int nf = 2 * n, cw = ch * 4 + w;
    float wacc = 0.f;
    for (int fi = cw; fi < nf; fi += 32) {
        int b = rows[fi >> 1], c = fi & 1;
        const float* xp = X + (size_t)b * 2048 + (size_t)c * 1024;
        float acc = 0.f;
#pragma unroll
        for (int c4 = 0; c4 < 4; ++c4) {
            int d0 = c4 * 256 + lane * 4;
            float4 xv = *(const float4*)(xp + d0);
            float4 cv = *(const float4*)&cent[d0];
            float dx = xv.x - cv.x, dy = xv.y - cv.y, dz = xv.z - cv.z, dw = xv.w - cv.w;
            acc += dx * dx + dy * dy + dz * dz + dw * dw;
        }
#pragma unroll
        for (int m = 32; m; m >>= 1) acc += __shfl_xor(acc, m, 64);
        if (lane == 0) wacc += sqrtf(sqrtf(acc));   // sqrt(dist), dist = sqrt(acc)
    }
    if (lane == 0 && wacc != 0.f) atomicAdd(&bsum, wacc);
    __syncthreads();
    if (t == 0) atomicAdd(&sqrtsum[g], bsum);
}

// K4: density post-processing (max/where, rank-based quantiles, clip, mean-normalize)
__global__ void k4_density(const float* __restrict__ sqrtsum,
                           const int* __restrict__ cnt,
                           float* __restrict__ recipDen) {
    __shared__ float tmp[KG];
    __shared__ float d1s[KG];
    __shared__ float qv[4];
    int g = threadIdx.x;
    float cntf = 2.f * (float)cnt[g];
    float d0 = (sqrtsum[g] / cntf) / logf(cntf + 10.f);
    tmp[g] = d0;
    __syncthreads();
    float dmax = -INFINITY;
    for (int j = 0; j < KG; ++j) dmax = fmaxf(dmax, tmp[j]);
    float v = (cntf <= 1.f) ? dmax : d0;
    d1s[g] = v;
    __syncthreads();
    int less = 0, eq = 0;
    for (int j = 0; j < KG; ++j) {
        float u = d1s[j];
        less += (u < v) ? 1 : 0;
        eq += (u == v) ? 1 : 0;
    }
    // quantile(0.1): idx 12.7 -> 0.3*v[12]+0.7*v[13]; quantile(0.9): idx 114.3 -> 0.7*v[114]+0.3*v[115]
    const int ppos[4] = {12, 13, 114, 115};
    for (int q = 0; q < 4; ++q)
        if (less <= ppos[q] && ppos[q] < less + eq) qv[q] = v;
    __syncthreads();
    float q10 = 0.3f * qv[0] + 0.7f * qv[1];
    float q90 = 0.7f * qv[2] + 0.3f * qv[3];
    float d2 = fminf(fmaxf(v, q10), q90);
    __syncthreads();
    tmp[g] = d2;
    __syncthreads();
    float sum = 0.f;
    for (int j = 0; j < KG; ++j) sum += tmp[j];
    float mean = sum / (float)KG;
    float den = 0.1f * d2 / mean;
    recipDen[g] = 1.f / den;
}

// K5: no-LDS MFMA GEMM + fused loss. Wave = 32 rows x 128 groups; fragments loaded
// directly from global in MFMA fragment order (A: fp32 + packed cvt; B: bf16 table).
// Register double-buffered over kc.
__global__ __launch_bounds__(256) void k5_loss(const float* __restrict__ X,
                                               const unsigned short* __restrict__ Cbf,
                                               const int* __restrict__ gid,
                                               const float* __restrict__ recipDen,
                                               float* __restrict__ out) {
    __shared__ float bs;
    if (threadIdx.x == 0) bs = 0.f;
    __syncthreads();
    int t = threadIdx.x, lane = t & 63;
    int gw = blockIdx.x * 4 + (t >> 6);
    int row0 = gw * 32;
    int m = lane & 15, q = lane >> 4;
    int r0 = row0 + m, r1 = row0 + 16 + m;
    const float* a0p = X + (size_t)(r0 & (BN - 1)) * 2048 + (size_t)(r0 >> 14) * 1024 + q * 8;
    const float* a1p = X + (size_t)(r1 & (BN - 1)) * 2048 + (size_t)(r1 >> 14) * 1024 + q * 8;
    const unsigned short* bp = Cbf + (size_t)m * DD + q * 8;

    v4f acc[2][8];
#pragma unroll
    for (int i = 0; i < 2; ++i)
#pragma unroll
        for (int j = 0; j < 8; ++j) acc[i][j] = (v4f){0.f, 0.f, 0.f, 0.f};

    float4 a0l = *(const float4*)(a0p), a0h = *(const float4*)(a0p + 4);
    float4 a1l = *(const float4*)(a1p), a1h = *(const float4*)(a1p + 4);
    short8v cb[8];
#pragma unroll
    for (int gt = 0; gt < 8; ++gt) cb[gt] = *(const short8v*)(bp + gt * 16 * DD);
    short8v ca0 = pack_bf8(a0l, a0h), ca1 = pack_bf8(a1l, a1h);

    for (int kc = 0; kc < 31; ++kc) {
        int k = (kc + 1) * 32;
        float4 na0l = *(const float4*)(a0p + k), na0h = *(const float4*)(a0p + k + 4);
        float4 na1l = *(const float4*)(a1p + k), na1h = *(const float4*)(a1p + k + 4);
        short8v nb[8];
#pragma unroll
        for (int gt = 0; gt < 8; ++gt) nb[gt] = *(const short8v*)(bp + gt * 16 * DD + k);
#pragma unroll
        for (int gt = 0; gt < 8; ++gt) {
            acc[0][gt] = __builtin_amdgcn_mfma_f32_16x16x32_bf16(ca0, cb[gt], acc[0][gt], 0, 0, 0);
            acc[1][gt] = __builtin_amdgcn_mfma_f32_16x16x32_bf16(ca1, cb[gt], acc[1][gt], 0, 0, 0);
        }
        ca0 = pack_bf8(na0l, na0h);
        ca1 = pack_bf8(na1l, na1h);
#pragma unroll
        for (int gt = 0; gt < 8; ++gt) cb[gt] = nb[gt];
    }
#pragma unroll
    for (int gt = 0; gt < 8; ++gt) {
        acc[0][gt] = __builtin_amdgcn_mfma_f32_16x16x32_bf16(ca0, cb[gt], acc[0][gt], 0, 0, 0);
        acc[1][gt] = __builtin_amdgcn_mfma_f32_16x16x32_bf16(ca1, cb[gt], acc[1][gt], 0, 0, 0);
    }

    // epilogue: C/D layout col = lane&15 (group), row = q*4 + reg
    float cden[8];
#pragma unroll
    for (int gt = 0; gt < 8; ++gt) cden[gt] = recipDen[gt * 16 + m];
    float ll = 0.f;
#pragma unroll
    for (int tile = 0; tile < 2; ++tile) {
#pragma unroll
        for (int reg = 0; reg < 4; ++reg) {
            int row = row0 + tile * 16 + q * 4 + reg;
            int b = row & (BN - 1);
            int gb = gid[b];
            int s = gb >> 3, l = gb & 7;
            float sim[8];
            float mx = -INFINITY;
#pragma unroll
            for (int gt = 0; gt < 8; ++gt) {
                sim[gt] = acc[tile][gt][reg] * cden[gt];
                mx = fmaxf(mx, sim[gt]);
            }
#pragma unroll
            for (int x = 1; x < 16; x <<= 1) mx = fmaxf(mx, __shfl_xor(mx, x, 64));
            float S = 0.f, P = 0.f;
#pragma unroll
            for (int gt = 0; gt < 8; ++gt) {
                int g = gt * 16 + m;
                if (((g & 7) == l) && ((g >> 3) != s)) {
                    float pv = sim[gt] - mx;
                    S += expf(pv);
                    P += pv;
                }
            }
#pragma unroll
            for (int x = 1; x < 16; x <<= 1) {
                S += __shfl_xor(S, x, 64);
                P += __shfl_xor(P, x, 64);
            }
            // 113 masked-out entries contribute exp(0)=1 each to the softmax denominator
            if (m == 0) ll += logf(113.f + S) - P * (1.f / 15.f);
        }
    }
    ll += __shfl_xor(ll, 16, 64);
    ll += __shfl_xor(ll, 32, 64);
    if (lane == 0) atomicAdd(&bs, ll);
    __syncthreads();
    if (t == 0) atomicAdd(out, bs * (1.f / 32768.f));
}

extern "C" void kernel_launch(void* const* d_in, const int* in_sizes, int n_in,
                              void* d_out, int out_size, void* d_ws, size_t ws_size,
                              hipStream_t stream) {
    const float* X = (const float*)d_in[0];
    const int* subject = (const int*)d_in[1];
    const int* labels = (const int*)d_in[2];
    float* out = (float*)d_out;
    char* w = (char*)d_ws;
    int* gid = (int*)(w + 0);                        // 64 KB
    int* cnt = (int*)(w + 65536);                    // 512 B
    int* offs = (int*)(w + 66048);                   // 512 B
    int* cursor = (int*)(w + 66560);                 // 512 B
    float* sqrtsum = (float*)(w + 67072);            // 512 B
    float* recipDen = (float*)(w + 67584);           // 512 B
    int* rowlist = (int*)(w + 131072);               // 64 KB
    float* centroid = (float*)(w + 262144);          // 512 KB
    unsigned short* Cbf = (unsigned short*)(w + 786432);  // 256 KB (total ~1 MB)

    hipMemsetAsync(cnt, 0, KG * sizeof(int), stream);
    hipMemsetAsync(sqrtsum, 0, KG * sizeof(float), stream);
    hipMemsetAsync(out, 0, sizeof(float), stream);

    k0_gid<<<16, 1024, 0, stream>>>(subject, labels, gid, cnt);
    k0b_offs<<<1, KG, 0, stream>>>(cnt, offs, cursor);
    k0c_scatter<<<16, 1024, 0, stream>>>(gid, cursor, rowlist);
    k1_centroid<<<KG * 4, 256, 0, stream>>>(X, rowlist, offs, cnt, centroid);
    k2b_cbf<<<KG * DD / 256, 256, 0, stream>>>(centroid, Cbf);
    k3_dist<<<KG * 8, 256, 0, stream>>>(X, rowlist, offs, cnt, centroid, sqrtsum);
    k4_density<<<1, KG, 0, stream>>>(sqrtsum, cnt, recipDen);
    k5_loss<<<256, 256, 0, stream>>>(X, Cbf, gid, recipDen, out);
}